// Round 4
// baseline (151.882 us; speedup 1.0000x reference)
//
#include <hip/hip_runtime.h>

// InstanceSegmentationLoss — single fused dispatch.
//
// The reference einsum over one-hot masks is a 33x33 joint histogram
// J[p][t] = #pixels(pred==p & true==t); everything downstream is O(33^2):
//   inter[n][m] = J[n][m]; psum = row sums; tsum = col sums
//   dummy = (sum_p p*rowsum[p] + sum_t t*colsum[t]) / 1e12
//   loss  = dummy + sum_n (1 - max_m iou[n][m])
//
// Fusion: per-block LDS histogram -> device-scope atomic flush to g_hist ->
// threadfence + atomic done-counter -> LAST block computes the loss and
// re-zeroes g_hist/g_done for the next call. g_hist/g_done are .bss
// (zeroed at module load), so the invariant "zero at kernel entry" holds on
// every call — identical work per call, graph-capture safe.
// d_ws is deliberately unused (R1/R2 container aborts suspected from d_ws).

#define NIDS  33            // ids 0..32 (0 = background)
#define HSIZE (NIDS * NIDS) // 1089

__device__ unsigned g_hist[HSIZE];  // zero-init (.bss), self-cleaned each call
__device__ unsigned g_done;         // likewise

__device__ __forceinline__ int clamp_id(float v) {
    int i = (int)v;
    i = i < 0 ? 0 : i;
    return i > (NIDS - 1) ? (NIDS - 1) : i;
}

__device__ __forceinline__ void bin4(unsigned* sh, float4 p, float4 t) {
    atomicAdd(&sh[clamp_id(p.x) * NIDS + clamp_id(t.x)], 1u);
    atomicAdd(&sh[clamp_id(p.y) * NIDS + clamp_id(t.y)], 1u);
    atomicAdd(&sh[clamp_id(p.z) * NIDS + clamp_id(t.z)], 1u);
    atomicAdd(&sh[clamp_id(p.w) * NIDS + clamp_id(t.w)], 1u);
}

__global__ void __launch_bounds__(512)
fused_loss_kernel(const float4* __restrict__ pred,
                  const float4* __restrict__ tmask,
                  float* __restrict__ out, int n4) {
    __shared__ unsigned sh[HSIZE];
    __shared__ bool is_last;

    const int tid = threadIdx.x;
    for (int i = tid; i < HSIZE; i += blockDim.x) sh[i] = 0u;
    __syncthreads();

    // ---- phase 1: per-block LDS histogram, 4-way unrolled float4 loads ----
    const int tot = gridDim.x * blockDim.x;
    int i = blockIdx.x * blockDim.x + tid;
    for (; i + 3 * tot < n4; i += 4 * tot) {
        float4 p0 = pred[i],           t0 = tmask[i];
        float4 p1 = pred[i + tot],     t1 = tmask[i + tot];
        float4 p2 = pred[i + 2 * tot], t2 = tmask[i + 2 * tot];
        float4 p3 = pred[i + 3 * tot], t3 = tmask[i + 3 * tot];
        bin4(sh, p0, t0);
        bin4(sh, p1, t1);
        bin4(sh, p2, t2);
        bin4(sh, p3, t3);
    }
    for (; i < n4; i += tot) bin4(sh, pred[i], tmask[i]);
    __syncthreads();

    // ---- phase 2: flush block histogram to global (device-scope atomics) ----
    for (int j = tid; j < HSIZE; j += blockDim.x) {
        unsigned v = sh[j];
        if (v) atomicAdd(&g_hist[j], v);
    }
    __threadfence();   // release: make this thread's atomics device-visible
    __syncthreads();   // all threads of the block have flushed + fenced

    if (tid == 0) {
        unsigned old = atomicAdd(&g_done, 1u);
        is_last = (old == gridDim.x - 1);
    }
    __syncthreads();
    if (!is_last) return;

    // ---- phase 3 (last block only): finalize ----
    __threadfence();   // acquire
    float* shf = (float*)sh;  // reuse LDS
    for (int j = tid; j < HSIZE; j += blockDim.x) {
        unsigned v = __hip_atomic_load(&g_hist[j], __ATOMIC_RELAXED,
                                       __HIP_MEMORY_SCOPE_AGENT);
        shf[j] = (float)v;
    }
    __syncthreads();

    // cleanup for next call (safe: next dispatch starts only after we finish)
    for (int j = tid; j < HSIZE; j += blockDim.x)
        __hip_atomic_store(&g_hist[j], 0u, __ATOMIC_RELAXED,
                           __HIP_MEMORY_SCOPE_AGENT);
    if (tid == 0)
        __hip_atomic_store(&g_done, 0u, __ATOMIC_RELAXED,
                           __HIP_MEMORY_SCOPE_AGENT);

    __shared__ float rowsum[NIDS], colsum[NIDS];
    __shared__ float maxv[32];
    if (tid < NIDS) {
        float rs = 0.f, cs = 0.f;
        for (int j = 0; j < NIDS; ++j) {
            rs += shf[tid * NIDS + j];
            cs += shf[j * NIDS + tid];
        }
        rowsum[tid] = rs;
        colsum[tid] = cs;
    }
    __syncthreads();

    if (tid < 32) {
        const int n = tid + 1;  // pred instance 1..32
        float best = 0.f;
        const float rs = rowsum[n];
        for (int m = 1; m < NIDS; ++m) {
            float inter = shf[n * NIDS + m];
            float uni   = rs + colsum[m] - inter;
            float iou   = (uni > 0.f) ? (inter / uni) : 0.f;
            best = fmaxf(best, iou);
        }
        maxv[tid] = best;
    }
    __syncthreads();

    if (tid == 0) {
        double sp = 0.0, st = 0.0;
        for (int k = 1; k < NIDS; ++k) {
            sp += (double)k * (double)rowsum[k];
            st += (double)k * (double)colsum[k];
        }
        float loss = 0.f;
        for (int k = 0; k < 32; ++k) loss += 1.0f - maxv[k];
        out[0] = loss + (float)((sp + st) * 1e-12);
    }
}

extern "C" void kernel_launch(void* const* d_in, const int* in_sizes, int n_in,
                              void* d_out, int out_size, void* d_ws, size_t ws_size,
                              hipStream_t stream) {
    const float* pred  = (const float*)d_in[0];
    const float* tmask = (const float*)d_in[1];
    float* out = (float*)d_out;

    const int n  = in_sizes[0];  // 2048*2048 = 4194304
    const int n4 = n / 4;

    // 512 blocks x 512 threads = 262144 threads -> 4 float4-pairs each;
    // 2 blocks/CU, 16 waves/CU, 8 outstanding 16B loads per lane.
    fused_loss_kernel<<<512, 512, 0, stream>>>((const float4*)pred,
                                               (const float4*)tmask, out, n4);
}

// Round 5
// 142.592 us; speedup vs baseline: 1.0652x; 1.0652x over previous
//
#include <hip/hip_runtime.h>

// InstanceSegmentationLoss — single fused dispatch, replica-spread flush.
//
// Reference == 33x33 joint histogram J[p][t] over 4.19M pixels + O(33^2) IoU.
//
// R4 post-mortem: 557K device-scope atomicAdds onto ONE 1089-word histogram
// (~68 cache lines) serialized at the coherence point (~100 us, all pipes
// idle: VALUBusy 0.8%, HBM 2%). Fix: 32 line-aligned replicas + half the
// blocks -> ~126 serialized atomics per line instead of ~8200.
//
// g_part/g_done are .bss (zero at load) and re-zeroed by the last block each
// call -> identical work every call, graph-capture safe. d_ws unused.

#define NIDS    33               // ids 0..32 (0 = background)
#define HSIZE   (NIDS * NIDS)    // 1089
#define RSTRIDE 1152             // 1089 padded to 64B-line multiple (u32 units)
#define NREP    32               // histogram replicas

__device__ unsigned g_part[NREP * RSTRIDE];  // zero-init, self-cleaned
__device__ unsigned g_done;                  // likewise

__device__ __forceinline__ int clamp_id(float v) {
    int i = (int)v;
    i = i < 0 ? 0 : i;
    return i > (NIDS - 1) ? (NIDS - 1) : i;
}

__device__ __forceinline__ void bin4(unsigned* sh, float4 p, float4 t) {
    atomicAdd(&sh[clamp_id(p.x) * NIDS + clamp_id(t.x)], 1u);
    atomicAdd(&sh[clamp_id(p.y) * NIDS + clamp_id(t.y)], 1u);
    atomicAdd(&sh[clamp_id(p.z) * NIDS + clamp_id(t.z)], 1u);
    atomicAdd(&sh[clamp_id(p.w) * NIDS + clamp_id(t.w)], 1u);
}

__global__ void __launch_bounds__(1024)
fused_loss_kernel(const float4* __restrict__ pred,
                  const float4* __restrict__ tmask,
                  float* __restrict__ out, int n4) {
    __shared__ unsigned sh[HSIZE];
    __shared__ bool is_last;

    const int tid = threadIdx.x;
    for (int i = tid; i < HSIZE; i += blockDim.x) sh[i] = 0u;
    __syncthreads();

    // ---- phase 1: per-block LDS histogram, 4-way unrolled float4 loads ----
    const int tot = gridDim.x * blockDim.x;   // 262144 -> exactly 4 float4/thread
    int i = blockIdx.x * blockDim.x + tid;
    for (; i + 3 * tot < n4; i += 4 * tot) {
        float4 p0 = pred[i],           t0 = tmask[i];
        float4 p1 = pred[i + tot],     t1 = tmask[i + tot];
        float4 p2 = pred[i + 2 * tot], t2 = tmask[i + 2 * tot];
        float4 p3 = pred[i + 3 * tot], t3 = tmask[i + 3 * tot];
        bin4(sh, p0, t0);
        bin4(sh, p1, t1);
        bin4(sh, p2, t2);
        bin4(sh, p3, t3);
    }
    for (; i < n4; i += tot) bin4(sh, pred[i], tmask[i]);
    __syncthreads();

    // ---- phase 2: flush to replica (blockIdx & 31) — spreads line traffic ----
    unsigned* rep = &g_part[(blockIdx.x & (NREP - 1)) * RSTRIDE];
    for (int j = tid; j < HSIZE; j += blockDim.x) {
        unsigned v = sh[j];
        if (v) atomicAdd(&rep[j], v);
    }
    __threadfence();   // release: atomics device-visible
    __syncthreads();

    if (tid == 0) {
        unsigned old = atomicAdd(&g_done, 1u);
        is_last = (old == gridDim.x - 1);
    }
    __syncthreads();
    if (!is_last) return;

    // ---- phase 3 (last block only): reduce replicas + finalize ----
    __threadfence();   // acquire
    float* shf = (float*)sh;  // reuse LDS
    for (int j = tid; j < HSIZE; j += blockDim.x) {
        unsigned s = 0u;
        #pragma unroll
        for (int r = 0; r < NREP; ++r)
            s += __hip_atomic_load(&g_part[r * RSTRIDE + j], __ATOMIC_RELAXED,
                                   __HIP_MEMORY_SCOPE_AGENT);
        shf[j] = (float)s;
    }
    __syncthreads();

    // cleanup for next call
    for (int j = tid; j < NREP * RSTRIDE; j += blockDim.x)
        __hip_atomic_store(&g_part[j], 0u, __ATOMIC_RELAXED,
                           __HIP_MEMORY_SCOPE_AGENT);
    if (tid == 0)
        __hip_atomic_store(&g_done, 0u, __ATOMIC_RELAXED,
                           __HIP_MEMORY_SCOPE_AGENT);

    __shared__ float rowsum[NIDS], colsum[NIDS];
    __shared__ float maxv[32];
    if (tid < NIDS) {
        float rs = 0.f, cs = 0.f;
        for (int j = 0; j < NIDS; ++j) {
            rs += shf[tid * NIDS + j];
            cs += shf[j * NIDS + tid];
        }
        rowsum[tid] = rs;
        colsum[tid] = cs;
    }
    __syncthreads();

    if (tid < 32) {
        const int n = tid + 1;  // pred instance 1..32
        float best = 0.f;
        const float rs = rowsum[n];
        for (int m = 1; m < NIDS; ++m) {
            float inter = shf[n * NIDS + m];
            float uni   = rs + colsum[m] - inter;
            float iou   = (uni > 0.f) ? (inter / uni) : 0.f;
            best = fmaxf(best, iou);
        }
        maxv[tid] = best;
    }
    __syncthreads();

    if (tid == 0) {
        double sp = 0.0, st = 0.0;
        for (int k = 1; k < NIDS; ++k) {
            sp += (double)k * (double)rowsum[k];
            st += (double)k * (double)colsum[k];
        }
        float loss = 0.f;
        for (int k = 0; k < 32; ++k) loss += 1.0f - maxv[k];
        out[0] = loss + (float)((sp + st) * 1e-12);
    }
}

extern "C" void kernel_launch(void* const* d_in, const int* in_sizes, int n_in,
                              void* d_out, int out_size, void* d_ws, size_t ws_size,
                              hipStream_t stream) {
    const float* pred  = (const float*)d_in[0];
    const float* tmask = (const float*)d_in[1];
    float* out = (float*)d_out;

    const int n  = in_sizes[0];  // 2048*2048 = 4194304
    const int n4 = n / 4;

    // 256 blocks x 1024 threads: ~1 block/CU, 16 waves/CU; exactly 4 float4
    // pairs per thread; flush = 279K atomics spread over 32 replicas.
    fused_loss_kernel<<<256, 1024, 0, stream>>>((const float4*)pred,
                                                (const float4*)tmask, out, n4);
}

// Round 8
// 88.301 us; speedup vs baseline: 1.7200x; 1.6148x over previous
//
#include <hip/hip_runtime.h>

// InstanceSegmentationLoss — single fused dispatch, replica flush,
// ONE-WAVE-per-block threadfence.
//
// Reference == 33x33 joint histogram J[p][t] over 4.19M pixels + O(33^2) IoU.
//
// History: R4/R5 (per-thread __threadfence) PASSED but the fence dominated
// (~65 us: agent-release emits per-wave XCD-L2 writeback; 4096 waves
// serialized — VALUBusy 1%, HBM 2.7%, all pipes idle). R6/R7 (fence fully
// removed) hit container failures 4x. This round keeps the R4/R5-proven
// ordering skeleton but issues the fence from ONE wave per block
// (256 fence-waves instead of 4096 -> ~1/16 the writeback serialization).
// Ordering is preserved: __syncthreads() before the fence has already
// drained every thread's flush atomics (compiler emits s_waitcnt vmcnt(0)
// before s_barrier [m97]); the single fence then publishes before the
// g_done increment, exactly as in R4/R5.
//
// g_part/g_done are .bss (zero at load), re-zeroed by the last block each
// call -> identical work every call, graph-capture safe. d_ws unused.

#define NIDS    33               // ids 0..32 (0 = background)
#define HSIZE   (NIDS * NIDS)    // 1089
#define RSTRIDE 1152             // 1089 padded to 64B-line multiple (u32 units)
#define NREP    32               // histogram replicas

__device__ unsigned g_part[NREP * RSTRIDE];  // zero-init, self-cleaned
__device__ unsigned g_done;                  // likewise

__device__ __forceinline__ int clamp_id(float v) {
    int i = (int)v;
    i = i < 0 ? 0 : i;
    return i > (NIDS - 1) ? (NIDS - 1) : i;
}

__device__ __forceinline__ void bin4(unsigned* sh, float4 p, float4 t) {
    atomicAdd(&sh[clamp_id(p.x) * NIDS + clamp_id(t.x)], 1u);
    atomicAdd(&sh[clamp_id(p.y) * NIDS + clamp_id(t.y)], 1u);
    atomicAdd(&sh[clamp_id(p.z) * NIDS + clamp_id(t.z)], 1u);
    atomicAdd(&sh[clamp_id(p.w) * NIDS + clamp_id(t.w)], 1u);
}

__global__ void __launch_bounds__(1024)
fused_loss_kernel(const float4* __restrict__ pred,
                  const float4* __restrict__ tmask,
                  float* __restrict__ out, int n4) {
    __shared__ unsigned sh[HSIZE];
    __shared__ bool is_last;

    const int tid = threadIdx.x;
    for (int i = tid; i < HSIZE; i += blockDim.x) sh[i] = 0u;
    __syncthreads();

    // ---- phase 1: per-block LDS histogram, 4-way unrolled float4 loads ----
    const int tot = gridDim.x * blockDim.x;   // 262144 -> exactly 4 float4/thread
    int i = blockIdx.x * blockDim.x + tid;
    for (; i + 3 * tot < n4; i += 4 * tot) {
        float4 p0 = pred[i],           t0 = tmask[i];
        float4 p1 = pred[i + tot],     t1 = tmask[i + tot];
        float4 p2 = pred[i + 2 * tot], t2 = tmask[i + 2 * tot];
        float4 p3 = pred[i + 3 * tot], t3 = tmask[i + 3 * tot];
        bin4(sh, p0, t0);
        bin4(sh, p1, t1);
        bin4(sh, p2, t2);
        bin4(sh, p3, t3);
    }
    for (; i < n4; i += tot) bin4(sh, pred[i], tmask[i]);
    __syncthreads();

    // ---- phase 2: flush to replica (blockIdx & 31) ----
    unsigned* rep = &g_part[(blockIdx.x & (NREP - 1)) * RSTRIDE];
    for (int j = tid; j < HSIZE; j += blockDim.x) {
        unsigned v = sh[j];
        if (v) atomicAdd(&rep[j], v);
    }
    __syncthreads();   // all waves' flush atomics drained (vmcnt(0)) [m97]

    if (tid < 64) __threadfence();   // ONE wave publishes (R4/R5 skeleton,
                                     // 1/16 the per-wave writeback cost)
    __syncthreads();

    if (tid == 0) {
        unsigned old = atomicAdd(&g_done, 1u);
        is_last = (old == gridDim.x - 1);
    }
    __syncthreads();
    if (!is_last) return;

    // ---- phase 3 (last block only): reduce replicas + finalize ----
    __threadfence();   // acquire side (one block, negligible)
    float* shf = (float*)sh;  // reuse LDS
    for (int j = tid; j < HSIZE; j += blockDim.x) {
        unsigned s = 0u;
        #pragma unroll
        for (int r = 0; r < NREP; ++r)
            s += __hip_atomic_load(&g_part[r * RSTRIDE + j], __ATOMIC_RELAXED,
                                   __HIP_MEMORY_SCOPE_AGENT);
        shf[j] = (float)s;
    }
    __syncthreads();

    // cleanup for next call (next dispatch starts only after kernel end)
    for (int j = tid; j < NREP * RSTRIDE; j += blockDim.x)
        __hip_atomic_store(&g_part[j], 0u, __ATOMIC_RELAXED,
                           __HIP_MEMORY_SCOPE_AGENT);
    if (tid == 0)
        __hip_atomic_store(&g_done, 0u, __ATOMIC_RELAXED,
                           __HIP_MEMORY_SCOPE_AGENT);

    __shared__ float rowsum[NIDS], colsum[NIDS];
    __shared__ float maxv[32];
    if (tid < NIDS) {
        float rs = 0.f, cs = 0.f;
        for (int j = 0; j < NIDS; ++j) {
            rs += shf[tid * NIDS + j];
            cs += shf[j * NIDS + tid];
        }
        rowsum[tid] = rs;
        colsum[tid] = cs;
    }
    __syncthreads();

    if (tid < 32) {
        const int n = tid + 1;  // pred instance 1..32
        float best = 0.f;
        const float rs = rowsum[n];
        for (int m = 1; m < NIDS; ++m) {
            float inter = shf[n * NIDS + m];
            float uni   = rs + colsum[m] - inter;
            float iou   = (uni > 0.f) ? (inter / uni) : 0.f;
            best = fmaxf(best, iou);
        }
        maxv[tid] = best;
    }
    __syncthreads();

    if (tid == 0) {
        double sp = 0.0, st = 0.0;
        for (int k = 1; k < NIDS; ++k) {
            sp += (double)k * (double)rowsum[k];
            st += (double)k * (double)colsum[k];
        }
        float loss = 0.f;
        for (int k = 0; k < 32; ++k) loss += 1.0f - maxv[k];
        out[0] = loss + (float)((sp + st) * 1e-12);
    }
}

extern "C" void kernel_launch(void* const* d_in, const int* in_sizes, int n_in,
                              void* d_out, int out_size, void* d_ws, size_t ws_size,
                              hipStream_t stream) {
    const float* pred  = (const float*)d_in[0];
    const float* tmask = (const float*)d_in[1];
    float* out = (float*)d_out;

    const int n  = in_sizes[0];  // 2048*2048 = 4194304
    const int n4 = n / 4;

    // 256 blocks x 1024 threads: 1 block/CU, 16 waves/CU; exactly 4 float4
    // pairs per thread; flush = 279K atomics spread over 32 replicas.
    fused_loss_kernel<<<256, 1024, 0, stream>>>((const float4*)pred,
                                                (const float4*)tmask, out, n4);
}

// Round 9
// 83.018 us; speedup vs baseline: 1.8295x; 1.0636x over previous
//
#include <hip/hip_runtime.h>

// InstanceSegmentationLoss — 2-dispatch form (R3-proven structure).
//
// Reference == 33x33 joint histogram J[p][t] over 4.19M pixels + O(33^2) IoU.
//
// R8 post-mortem: fused single-dispatch works (dur 88.3) but ~10 us of the
// ~25 us kernel is spent emulating a dispatch boundary (one-wave threadfence
// ~4 us + 256-way done-counter ~3 us + last-block tail ~3 us). The
// 2-dispatch form gets ordering/visibility for free: dispatch boundary
// orders hist->finalize, and ALL cross-dispatch data moves via agent-scope
// atomics executed at the LLC (bypassing the non-coherent per-XCD L2s),
// so no fence is needed anywhere — the structure that passed R3 twice and
// never container-failed.
//
// g_part is .bss (zero at load); finalize re-zeroes it (agent-scope atomic
// stores, visible at LLC) each call -> zero-at-entry invariant holds on
// every graph replay. Identical work every call; d_ws unused.

#define NIDS    33               // ids 0..32 (0 = background)
#define HSIZE   (NIDS * NIDS)    // 1089
#define RSTRIDE 1152             // 1089 padded to 64B-line multiple (u32 units)
#define NREP    32               // histogram replicas (spread LLC line traffic)

__device__ unsigned g_part[NREP * RSTRIDE];  // zero-init, self-cleaned

__device__ __forceinline__ int clamp_id(float v) {
    int i = (int)v;
    i = i < 0 ? 0 : i;
    return i > (NIDS - 1) ? (NIDS - 1) : i;
}

__device__ __forceinline__ void bin4(unsigned* sh, float4 p, float4 t) {
    atomicAdd(&sh[clamp_id(p.x) * NIDS + clamp_id(t.x)], 1u);
    atomicAdd(&sh[clamp_id(p.y) * NIDS + clamp_id(t.y)], 1u);
    atomicAdd(&sh[clamp_id(p.z) * NIDS + clamp_id(t.z)], 1u);
    atomicAdd(&sh[clamp_id(p.w) * NIDS + clamp_id(t.w)], 1u);
}

__global__ void __launch_bounds__(1024)
hist_kernel(const float4* __restrict__ pred,
            const float4* __restrict__ tmask, int n4) {
    __shared__ unsigned sh[HSIZE];

    const int tid = threadIdx.x;
    for (int i = tid; i < HSIZE; i += blockDim.x) sh[i] = 0u;
    __syncthreads();

    // per-block LDS histogram, 4-way unrolled float4 loads
    const int tot = gridDim.x * blockDim.x;   // 262144 -> exactly 4 float4/thread
    int i = blockIdx.x * blockDim.x + tid;
    for (; i + 3 * tot < n4; i += 4 * tot) {
        float4 p0 = pred[i],           t0 = tmask[i];
        float4 p1 = pred[i + tot],     t1 = tmask[i + tot];
        float4 p2 = pred[i + 2 * tot], t2 = tmask[i + 2 * tot];
        float4 p3 = pred[i + 3 * tot], t3 = tmask[i + 3 * tot];
        bin4(sh, p0, t0);
        bin4(sh, p1, t1);
        bin4(sh, p2, t2);
        bin4(sh, p3, t3);
    }
    for (; i < n4; i += tot) bin4(sh, pred[i], tmask[i]);
    __syncthreads();

    // flush to replica (blockIdx & 31): agent-scope atomics at the LLC.
    // No fence — the dispatch boundary orders this vs finalize_kernel.
    unsigned* rep = &g_part[(blockIdx.x & (NREP - 1)) * RSTRIDE];
    for (int j = tid; j < HSIZE; j += blockDim.x) {
        unsigned v = sh[j];
        if (v) atomicAdd(&rep[j], v);
    }
}

__global__ void __launch_bounds__(1024)
finalize_kernel(float* __restrict__ out) {
    __shared__ float shf[HSIZE];
    __shared__ float rowsum[NIDS], colsum[NIDS];
    __shared__ float maxv[32];

    const int tid = threadIdx.x;
    // reduce 32 replicas (agent-scope loads at LLC — always coherent)
    for (int j = tid; j < HSIZE; j += blockDim.x) {
        unsigned s = 0u;
        #pragma unroll
        for (int r = 0; r < NREP; ++r)
            s += __hip_atomic_load(&g_part[r * RSTRIDE + j], __ATOMIC_RELAXED,
                                   __HIP_MEMORY_SCOPE_AGENT);
        shf[j] = (float)s;
    }
    // re-zero for next call (agent-scope stores -> land at LLC, next call's
    // flush atomics see them)
    for (int j = tid; j < NREP * RSTRIDE; j += blockDim.x)
        __hip_atomic_store(&g_part[j], 0u, __ATOMIC_RELAXED,
                           __HIP_MEMORY_SCOPE_AGENT);
    __syncthreads();

    if (tid < NIDS) {
        float rs = 0.f, cs = 0.f;
        for (int j = 0; j < NIDS; ++j) {
            rs += shf[tid * NIDS + j];
            cs += shf[j * NIDS + tid];
        }
        rowsum[tid] = rs;
        colsum[tid] = cs;
    }
    __syncthreads();

    if (tid < 32) {
        const int n = tid + 1;  // pred instance 1..32
        float best = 0.f;
        const float rs = rowsum[n];
        for (int m = 1; m < NIDS; ++m) {
            float inter = shf[n * NIDS + m];
            float uni   = rs + colsum[m] - inter;
            float iou   = (uni > 0.f) ? (inter / uni) : 0.f;
            best = fmaxf(best, iou);
        }
        maxv[tid] = best;
    }
    __syncthreads();

    if (tid == 0) {
        double sp = 0.0, st = 0.0;
        for (int k = 1; k < NIDS; ++k) {
            sp += (double)k * (double)rowsum[k];
            st += (double)k * (double)colsum[k];
        }
        float loss = 0.f;
        for (int k = 0; k < 32; ++k) loss += 1.0f - maxv[k];
        out[0] = loss + (float)((sp + st) * 1e-12);
    }
}

extern "C" void kernel_launch(void* const* d_in, const int* in_sizes, int n_in,
                              void* d_out, int out_size, void* d_ws, size_t ws_size,
                              hipStream_t stream) {
    const float* pred  = (const float*)d_in[0];
    const float* tmask = (const float*)d_in[1];
    float* out = (float*)d_out;

    const int n  = in_sizes[0];  // 2048*2048 = 4194304
    const int n4 = n / 4;

    // 256 blocks x 1024 threads: 1 block/CU, 16 waves/CU; exactly 4 float4
    // pairs per thread; flush = 279K atomics spread over 32 replicas.
    hist_kernel<<<256, 1024, 0, stream>>>((const float4*)pred,
                                          (const float4*)tmask, n4);
    finalize_kernel<<<1, 1024, 0, stream>>>(out);
}